// Round 1
// 1954.632 us; speedup vs baseline: 1.9015x; 1.9015x over previous
//
#include <hip/hip_runtime.h>
#include <math.h>

#define TPB 256

typedef __attribute__((ext_vector_type(8))) short s8v;   // 8 bf16 (MFMA A/B frag)
typedef __attribute__((ext_vector_type(4))) float f4v;   // 4 f32 (MFMA C/D frag)

__device__ __forceinline__ unsigned bf16r(float f) {
  unsigned u = __float_as_uint(f);
  return (u + 0x7fffu + ((u >> 16) & 1u)) >> 16;  // RNE fp32->bf16
}

// ---------------------------------------------------------------------------
// Per-sample separable 1D gaussian kernels (normalized), all 3 levels at once.
// ---------------------------------------------------------------------------
__global__ __launch_bounds__(128) void gauss1d_kernel(const float* __restrict__ alphas,
                                                      float* __restrict__ k1d) {
  int t = threadIdx.x;
  if (t >= 108) return;
  int lvl = t / 36;
  int rem = t - lvl * 36;
  int b = rem / 9;
  int j = rem - b * 9;
  float alpha = alphas[b * 3 + lvl];
  float k = floorf(floorf(alpha * 8.f) * 0.5f) * 2.f + 1.f;
  float r = (k - 1.f) * 0.5f;
  float sum = 0.f, val = 0.f;
  for (int u = 0; u < 9; ++u) {
    float d = (float)(u - 4);
    float g = expf(-(d * d) / 512.f);   // 2*sigma^2 = 512
    if (fabsf(d) > r) g = 0.f;
    if (u == j) val = g;
    sum += g;
  }
  k1d[(lvl * 4 + b) * 9 + j] = val / sum;
}

// ---------------------------------------------------------------------------
// Per-(b,c) mean + unbiased std over HW. One block per (b,c).
// ---------------------------------------------------------------------------
__global__ __launch_bounds__(TPB) void stats_kernel(const float* __restrict__ x,
                                                    float* __restrict__ mean,
                                                    float* __restrict__ stdv, int HW) {
  long long base = (long long)blockIdx.x * HW;
  float s = 0.f, q = 0.f;
  for (int i = threadIdx.x; i < HW; i += TPB) {
    float v = x[base + i];
    s += v;
    q = fmaf(v, v, q);
  }
#pragma unroll
  for (int off = 32; off > 0; off >>= 1) {
    s += __shfl_down(s, off, 64);
    q += __shfl_down(q, off, 64);
  }
  __shared__ float sm[8];
  int w = threadIdx.x >> 6, lane = threadIdx.x & 63;
  if (lane == 0) { sm[w * 2] = s; sm[w * 2 + 1] = q; }
  __syncthreads();
  if (threadIdx.x == 0) {
    float S = sm[0] + sm[2] + sm[4] + sm[6];
    float Q = sm[1] + sm[3] + sm[5] + sm[7];
    float m = S / (float)HW;
    float var = (Q - S * m) / (float)(HW - 1);
    mean[blockIdx.x] = m;
    stdv[blockIdx.x] = sqrtf(fmaxf(var, 0.f));
  }
}

// ---------------------------------------------------------------------------
// 2x2 mean pool
// ---------------------------------------------------------------------------
__global__ __launch_bounds__(TPB) void pool2_kernel(const float* __restrict__ src,
                                                    float* __restrict__ dst,
                                                    int lwh, int lhh, long long n) {
  long long i = (long long)blockIdx.x * TPB + threadIdx.x;
  if (i >= n) return;
  int Wh = 1 << lwh, Hh = 1 << lhh;
  int px = (int)(i & (Wh - 1));
  int py = (int)((i >> lwh) & (Hh - 1));
  long long bc = i >> (lwh + lhh);
  const float* sp = src + (bc << (lwh + lhh + 2)) + (long long)(py * 2) * (Wh * 2) + px * 2;
  dst[i] = 0.25f * (sp[0] + sp[1] + sp[Wh * 2] + sp[Wh * 2 + 1]);
}

// ---------------------------------------------------------------------------
// Nearest 2x upsample. lw/lh log2 of OUTPUT dims.
// ---------------------------------------------------------------------------
__global__ __launch_bounds__(TPB) void up2_kernel(const float* __restrict__ src,
                                                  float* __restrict__ dst,
                                                  int lw, int lh, long long n) {
  long long i = (long long)blockIdx.x * TPB + threadIdx.x;
  if (i >= n) return;
  int Wo = 1 << lw, Ho = 1 << lh;
  int x = (int)(i & (Wo - 1));
  int y = (int)((i >> lw) & (Ho - 1));
  long long bc = i >> (lw + lh);
  dst[i] = src[(bc << (lw + lh - 2)) + (long long)(y >> 1) * (Wo >> 1) + (x >> 1)];
}

// ---------------------------------------------------------------------------
// blurX of hh(c) (pool precomputed)
// ---------------------------------------------------------------------------
__global__ __launch_bounds__(TPB) void blurx_kernel(const float* __restrict__ src,
                                                    const float* __restrict__ pmap,
                                                    const float* __restrict__ k1d,
                                                    float* __restrict__ dst,
                                                    int C, int lw, int lh) {
  int b = blockIdx.z;
  float kb[9];
#pragma unroll
  for (int t = 0; t < 9; ++t) kb[t] = k1d[b * 9 + t];
  int W = 1 << lw;
  long long i = (long long)blockIdx.x * TPB + threadIdx.x;
  long long nper = (long long)C << (lw + lh);
  if (i >= nper) return;
  int x = (int)(i & (W - 1));
  long long rest = i >> lw;
  int y = (int)(rest & ((1 << lh) - 1));
  int c = (int)(rest >> lh);
  long long bc = (long long)b * C + c;
  const float* sp = src + (bc << (lw + lh)) + ((long long)y << lw);
  const float* pp = pmap + (bc << (lw + lh - 2)) + ((long long)(y >> 1) << (lw - 1));
  float s = 0.f;
#pragma unroll
  for (int t = 0; t < 9; ++t) {
    int px = x + t - 4;
    px = px < 0 ? 0 : (px > W - 1 ? W - 1 : px);
    s = fmaf(kb[t], sp[px] - pp[px >> 1], s);
  }
  dst[(bc << (lw + lh)) + ((long long)y << lw) + x] = s;
}

// ---------------------------------------------------------------------------
// blurY + scale + add
// ---------------------------------------------------------------------------
__global__ __launch_bounds__(TPB) void blury_add_kernel(const float* __restrict__ tmp,
                                                        float* __restrict__ out,
                                                        const float* __restrict__ k1d,
                                                        const float* __restrict__ stdc,
                                                        const float* __restrict__ stds,
                                                        int C, int lw, int lh) {
  int b = blockIdx.z;
  float kb[9];
#pragma unroll
  for (int t = 0; t < 9; ++t) kb[t] = k1d[b * 9 + t];
  int W = 1 << lw, H = 1 << lh;
  long long i = (long long)blockIdx.x * TPB + threadIdx.x;
  long long nper = (long long)C << (lw + lh);
  if (i >= nper) return;
  int x = (int)(i & (W - 1));
  long long rest = i >> lw;
  int y = (int)(rest & (H - 1));
  int c = (int)(rest >> lh);
  int bc = b * C + c;
  float a = stds[bc] / (stdc[bc] + 1e-5f);
  const float* tp = tmp + ((long long)bc << (lw + lh)) + x;
  float s = 0.f;
#pragma unroll
  for (int t = 0; t < 9; ++t) {
    int py = y + t - 4;
    py = py < 0 ? 0 : (py > H - 1 ? H - 1 : py);
    s = fmaf(kb[t], tp[(long long)py << lw], s);
  }
  out[((long long)bc << (lw + lh)) + ((long long)y << lw) + x] += a * s;
}

// ---------------------------------------------------------------------------
// In-place AdaIN affine
// ---------------------------------------------------------------------------
__global__ __launch_bounds__(TPB) void affine_kernel(float* __restrict__ x,
                                                     const float* __restrict__ mc,
                                                     const float* __restrict__ sc,
                                                     const float* __restrict__ ms,
                                                     const float* __restrict__ ss, int HW) {
  int bc = blockIdx.y;
  float a = ss[bc] / (sc[bc] + 1e-5f);
  float d = ms[bc] - mc[bc] * a;
  long long base = (long long)bc * HW;
  for (int i = blockIdx.x * TPB + threadIdx.x; i < HW; i += gridDim.x * TPB)
    x[base + i] = fmaf(x[base + i], a, d);
}

// ---------------------------------------------------------------------------
// bias + relu (epilogue for split-K atomic convs)
// ---------------------------------------------------------------------------
__global__ __launch_bounds__(TPB) void bias_relu_kernel(float* __restrict__ x,
                                                        const float* __restrict__ bias,
                                                        int HW, int C, long long n) {
  long long i = (long long)blockIdx.x * TPB + threadIdx.x;
  if (i >= n) return;
  int c = (int)((i / HW) % C);
  x[i] = fmaxf(x[i] + bias[c], 0.f);
}

// ---------------------------------------------------------------------------
// Weight pre-split: fp32 [Cout][Cin][3][3] -> bf16 hi/lo planes laid out in
// MFMA A-fragment order: plane[( (t*(Cout/16)+cof)*(Cin/32)+cik )*512 + lane*8 + j]
//   co = cof*16 + (lane&15), ci = cik*32 + (lane>>4)*8 + j
// ---------------------------------------------------------------------------
__global__ __launch_bounds__(TPB) void wsplit_kernel(const float* __restrict__ w,
                                                     short* __restrict__ wt,
                                                     int Cin, int Cout) {
  int nk = Cin >> 5, nc = Cout >> 4;
  int nf = 9 * nc * nk;
  int total = nf << 6;
  int planeStride = nf << 9;  // shorts
  for (int i = blockIdx.x * TPB + threadIdx.x; i < total; i += gridDim.x * TPB) {
    int l = i & 63;
    int f = i >> 6;
    int cik = f % nk;
    int rem = f / nk;
    int cof = rem % nc;
    int t = rem / nc;
    int co = (cof << 4) + (l & 15);
    int ci = (cik << 5) + ((l >> 4) << 3);
    s8v hv, lv;
#pragma unroll
    for (int j = 0; j < 8; ++j) {
      float v = w[((long long)co * Cin + ci + j) * 9 + t];
      unsigned h = bf16r(v);
      float r = v - __uint_as_float(h << 16);
      hv[j] = (short)h;
      lv[j] = (short)bf16r(r);
    }
    long long o = ((long long)f << 9) + (l << 3);
    *(s8v*)(wt + o) = hv;
    *(s8v*)(wt + planeStride + o) = lv;
  }
}

// ---------------------------------------------------------------------------
// bf16x2-split (3-MFMA) implicit-GEMM 3x3 conv, reflect pad 1, NCHW fp32.
// Block: 32 co x 256 px (16x16 spatial). 4 waves, each 32co x 64px
// (m=2 x n=4 frags of mfma_f32_16x16x32_bf16). K = ci, chunks of 32;
// 9 taps = 9 accumulation passes over shifted LDS reads.
// Input chunk staged as hi/lo bf16 planes [18][18][ci pad 40] (single
// ds_read_b128 per B-frag, 2-way bank aliasing only). Weights read as
// coalesced 16B global loads from pre-split fragment-ordered planes.
// ---------------------------------------------------------------------------
template <bool RELU, bool ATOMIC>
__global__ __launch_bounds__(TPB, 3) void conv_mfma_kernel(
    const float* __restrict__ in, const short* __restrict__ wt,
    const float* __restrict__ bias, float* __restrict__ out,
    int Cin, int Cout, int H, int W, int ciPer, int ksplit) {
  __shared__ __align__(16) short sIn[2][12960];  // 18*18*40 shorts per plane

  const int tid = threadIdx.x;
  const int l = tid & 63;
  const int wv = tid >> 6;
  const int xln = l & 15;
  const int kg = l >> 4;
  const int tilesX = W >> 4;
  const int tx0 = (blockIdx.x % tilesX) << 4;
  const int ty0 = (blockIdx.x / tilesX) << 4;
  const int co0 = blockIdx.y << 5;
  const int b = blockIdx.z / ksplit;
  const int kz = blockIdx.z % ksplit;
  const int ci0 = kz * ciPer;
  const long long HW = (long long)H * W;
  const long long inB = (long long)b * Cin * HW;

  const int nk = Cin >> 5;
  const int nc = Cout >> 4;
  const int planeStride = (9 * nc * nk) << 9;  // shorts

  f4v acc[2][4];
#pragma unroll
  for (int m = 0; m < 2; ++m)
#pragma unroll
    for (int n = 0; n < 4; ++n) acc[m][n] = (f4v){0.f, 0.f, 0.f, 0.f};

  const int bOff = ((wv * 4) * 18 + xln) * 40 + kg * 8;  // short offset, n=r=c=0

  for (int cc = 0; cc < ciPer; cc += 32) {
    const int cib = ci0 + cc;
    __syncthreads();
    // ---- stage input chunk: 18x18 x 32ci, hi/lo bf16, ci pairs packed ----
    for (int i = tid; i < 5184; i += TPB) {   // 18*18*16 pair tasks
      int ix = i % 18;
      int rem = i / 18;
      int cp = rem & 15;
      int iy = rem >> 4;
      int gy = ty0 - 1 + iy;
      gy = gy < 0 ? -gy : (gy >= H ? 2 * H - 2 - gy : gy);
      int gx = tx0 - 1 + ix;
      gx = gx < 0 ? -gx : (gx >= W ? 2 * W - 2 - gx : gx);
      long long gp = inB + (long long)(cib + cp * 2) * HW + (long long)gy * W + gx;
      float f0 = in[gp], f1 = in[gp + HW];
      unsigned h0 = bf16r(f0), h1 = bf16r(f1);
      unsigned lo0 = bf16r(f0 - __uint_as_float(h0 << 16));
      unsigned lo1 = bf16r(f1 - __uint_as_float(h1 << 16));
      int idx = (iy * 18 + ix) * 40 + cp * 2;
      *(unsigned*)&sIn[0][idx] = h0 | (h1 << 16);
      *(unsigned*)&sIn[1][idx] = lo0 | (lo1 << 16);
    }
    __syncthreads();

    const int cik = cib >> 5;
#pragma unroll
    for (int t = 0; t < 9; ++t) {
      const int r = t / 3, c = t % 3;
      s8v ah[2], al[2];
#pragma unroll
      for (int m = 0; m < 2; ++m) {
        int f = (t * nc + ((co0 >> 4) + m)) * nk + cik;
        const short* wp = wt + ((long long)f << 9) + (l << 3);
        ah[m] = *(const s8v*)wp;
        al[m] = *(const s8v*)(wp + planeStride);
      }
#pragma unroll
      for (int n = 0; n < 4; ++n) {
        int o = bOff + ((n + r) * 18 + c) * 40;
        s8v bh = *(const s8v*)&sIn[0][o];
        s8v bl = *(const s8v*)&sIn[1][o];
#pragma unroll
        for (int m = 0; m < 2; ++m) {
          acc[m][n] = __builtin_amdgcn_mfma_f32_16x16x32_bf16(ah[m], bh, acc[m][n], 0, 0, 0);
          acc[m][n] = __builtin_amdgcn_mfma_f32_16x16x32_bf16(ah[m], bl, acc[m][n], 0, 0, 0);
          acc[m][n] = __builtin_amdgcn_mfma_f32_16x16x32_bf16(al[m], bh, acc[m][n], 0, 0, 0);
        }
      }
    }
  }

  // ---- epilogue: C/D layout col=lane&15 (px-x), row=(lane>>4)*4+reg (co) ----
#pragma unroll
  for (int m = 0; m < 2; ++m) {
    const int cb = co0 + m * 16 + kg * 4;
#pragma unroll
    for (int j = 0; j < 4; ++j) {
      const int co = cb + j;
      const float bv = ATOMIC ? 0.f : bias[co];
#pragma unroll
      for (int n = 0; n < 4; ++n) {
        long long oadr = ((long long)b * Cout + co) * HW +
                         (long long)(ty0 + wv * 4 + n) * W + tx0 + xln;
        float v = acc[m][n][j];
        if (ATOMIC) {
          atomicAdd(&out[oadr], v);
        } else {
          v += bv;
          if (RELU) v = fmaxf(v, 0.f);
          out[oadr] = v;
        }
      }
    }
  }
}

// ---------------------------------------------------------------------------
// Small final conv: Cout=3 (fp32 path, unchanged)
// ---------------------------------------------------------------------------
__global__ __launch_bounds__(TPB) void conv3x3_c3_kernel(
    const float* __restrict__ in, const float* __restrict__ wgt,
    const float* __restrict__ bias, float* __restrict__ out,
    int Cin, int H, int W) {
  __shared__ __align__(16) float tIn[8][18][20];
  const int tid = threadIdx.x;
  const int tilesX = W >> 4;
  const int tx0 = (blockIdx.x % tilesX) << 4;
  const int ty0 = (blockIdx.x / tilesX) << 4;
  const int b = blockIdx.z;
  const int tx = tid & 15, ty = tid >> 4;

  float acc[3] = {0.f, 0.f, 0.f};
  const long long inB = (long long)b * Cin * H * W;

  for (int cc = 0; cc < Cin; cc += 8) {
    __syncthreads();
    for (int i = tid; i < 8 * 324; i += TPB) {
      int ci = i / 324;
      int rem = i - ci * 324;
      int iy = rem / 18;
      int ix = rem - iy * 18;
      int gy = ty0 - 1 + iy;
      gy = gy < 0 ? -gy : (gy >= H ? 2 * H - 2 - gy : gy);
      int gx = tx0 - 1 + ix;
      gx = gx < 0 ? -gx : (gx >= W ? 2 * W - 2 - gx : gx);
      tIn[ci][iy][ix] = in[inB + (long long)(cc + ci) * H * W + (long long)gy * W + gx];
    }
    __syncthreads();
#pragma unroll 2
    for (int ci = 0; ci < 8; ++ci) {
#pragma unroll
      for (int r = 0; r < 3; ++r)
#pragma unroll
        for (int c = 0; c < 3; ++c) {
          float v = tIn[ci][ty + r][tx + c];
          int t = r * 3 + c;
          acc[0] = fmaf(wgt[((long long)(0 * Cin) + cc + ci) * 9 + t], v, acc[0]);
          acc[1] = fmaf(wgt[((long long)(1 * Cin) + cc + ci) * 9 + t], v, acc[1]);
          acc[2] = fmaf(wgt[((long long)(2 * Cin) + cc + ci) * 9 + t], v, acc[2]);
        }
    }
  }
  const long long HWl = (long long)H * W;
#pragma unroll
  for (int co = 0; co < 3; ++co)
    out[((long long)b * 3 + co) * HWl + (long long)(ty0 + ty) * W + tx0 + tx] =
        acc[co] + bias[co];
}

// ---------------------------------------------------------------------------
static inline void launch_conv_mfma(const float* in, const float* w, const float* bias,
                                    float* out, short* wsc, int Cin, int Cout,
                                    int H, int W, int ksplit, hipStream_t s) {
  int total = 9 * (Cout >> 4) * (Cin >> 5) * 64;
  int wgrid = (total + TPB - 1) / TPB;
  wsplit_kernel<<<wgrid, TPB, 0, s>>>(w, wsc, Cin, Cout);
  dim3 grid((W >> 4) * (H >> 4), Cout >> 5, 4 * ksplit);
  if (ksplit > 1)
    conv_mfma_kernel<false, true><<<grid, TPB, 0, s>>>(in, wsc, bias, out, Cin, Cout,
                                                       H, W, Cin / ksplit, ksplit);
  else
    conv_mfma_kernel<true, false><<<grid, TPB, 0, s>>>(in, wsc, bias, out, Cin, Cout,
                                                       H, W, Cin, 1);
}

extern "C" void kernel_launch(void* const* d_in, const int* in_sizes, int n_in,
                              void* d_out, int out_size, void* d_ws, size_t ws_size,
                              hipStream_t stream) {
  const float* x   = (const float*)d_in[0];
  const float* c34 = (const float*)d_in[1];
  const float* c22 = (const float*)d_in[2];
  const float* c12 = (const float*)d_in[3];
  const float* s34 = (const float*)d_in[4];
  const float* s31 = (const float*)d_in[5];
  const float* s22 = (const float*)d_in[6];
  const float* s21 = (const float*)d_in[7];
  const float* s12 = (const float*)d_in[8];
  const float* s11 = (const float*)d_in[9];
  const float* alphas = (const float*)d_in[10];
  const float* w41 = (const float*)d_in[11]; const float* b41 = (const float*)d_in[12];
  const float* w34 = (const float*)d_in[13]; const float* b34 = (const float*)d_in[14];
  const float* w33 = (const float*)d_in[15]; const float* b33 = (const float*)d_in[16];
  const float* w32 = (const float*)d_in[17]; const float* b32 = (const float*)d_in[18];
  const float* w31 = (const float*)d_in[19]; const float* b31 = (const float*)d_in[20];
  const float* w22 = (const float*)d_in[21]; const float* b22 = (const float*)d_in[22];
  const float* w21 = (const float*)d_in[23]; const float* b21 = (const float*)d_in[24];
  const float* w12 = (const float*)d_in[25]; const float* b12 = (const float*)d_in[26];
  const float* w11 = (const float*)d_in[27]; const float* b11 = (const float*)d_in[28];

  // workspace layout (floats)
  float* A  = (float*)d_ws;            // 16M floats (64 MB)
  float* Bb = A + 16777216;            // 16M floats (64 MB)
  float* P  = Bb + 16777216;           // 4M floats (16 MB): pool map / wsplit scratch
  float* mc = P + 4194304;
  float* sc = mc + 2048;
  float* ms = sc + 2048;
  float* ss = ms + 2048;
  float* k1 = ss + 2048;               // 108 floats: [3][4][9]
  short* wsc = (short*)P;              // split-weight scratch (max 4.72 MB, fits in P)

  gauss1d_kernel<<<1, 128, 0, stream>>>(alphas, k1);

  // ---------------- level 4 -> 3 (64x64, 256ch) ----------------
  hipMemsetAsync(A, 0, 4LL * 256 * 32 * 32 * 4, stream);
  launch_conv_mfma(x, w41, b41, A, wsc, 512, 256, 32, 32, 4, stream);
  {
    long long n = 4LL * 256 * 1024;
    bias_relu_kernel<<<(int)(n / TPB), TPB, 0, stream>>>(A, b41, 1024, 256, n);
  }
  {
    long long n = 4LL * 256 * 64 * 64;
    up2_kernel<<<(int)(n / TPB), TPB, 0, stream>>>(A, Bb, 6, 6, n);
  }
  stats_kernel<<<4 * 256, TPB, 0, stream>>>(c34, mc, sc, 64 * 64);
  stats_kernel<<<4 * 256, TPB, 0, stream>>>(s34, ms, ss, 64 * 64);
  {
    long long n = 4LL * 256 * 32 * 32;
    pool2_kernel<<<(int)(n / TPB), TPB, 0, stream>>>(c34, P, 5, 5, n);
  }
  {
    dim3 g((unsigned)((256LL * 64 * 64) / TPB), 1, 4);
    blurx_kernel<<<g, TPB, 0, stream>>>(c34, P, k1 + 72, A, 256, 6, 6);
    blury_add_kernel<<<g, TPB, 0, stream>>>(A, Bb, k1 + 72, sc, ss, 256, 6, 6);
  }
  launch_conv_mfma(Bb, w34, b34, A, wsc, 256, 256, 64, 64, 1, stream);
  launch_conv_mfma(A, w33, b33, Bb, wsc, 256, 256, 64, 64, 1, stream);
  launch_conv_mfma(Bb, w32, b32, A, wsc, 256, 256, 64, 64, 1, stream);
  stats_kernel<<<4 * 256, TPB, 0, stream>>>(A, mc, sc, 64 * 64);
  stats_kernel<<<4 * 256, TPB, 0, stream>>>(s31, ms, ss, 64 * 64);
  {
    dim3 g(16, 4 * 256);
    affine_kernel<<<g, TPB, 0, stream>>>(A, mc, sc, ms, ss, 64 * 64);
  }
  hipMemsetAsync(Bb, 0, 4LL * 128 * 64 * 64 * 4, stream);
  launch_conv_mfma(A, w31, b31, Bb, wsc, 256, 128, 64, 64, 2, stream);
  {
    long long n = 4LL * 128 * 4096;
    bias_relu_kernel<<<(int)(n / TPB), TPB, 0, stream>>>(Bb, b31, 4096, 128, n);
  }

  // ---------------- level 3 -> 2 (128x128, 128ch) ----------------
  {
    long long n = 4LL * 128 * 128 * 128;
    up2_kernel<<<(int)(n / TPB), TPB, 0, stream>>>(Bb, A, 7, 7, n);
  }
  stats_kernel<<<4 * 128, TPB, 0, stream>>>(c22, mc, sc, 128 * 128);
  stats_kernel<<<4 * 128, TPB, 0, stream>>>(s22, ms, ss, 128 * 128);
  {
    long long n = 4LL * 128 * 64 * 64;
    pool2_kernel<<<(int)(n / TPB), TPB, 0, stream>>>(c22, P, 6, 6, n);
  }
  {
    dim3 g((unsigned)((128LL * 128 * 128) / TPB), 1, 4);
    blurx_kernel<<<g, TPB, 0, stream>>>(c22, P, k1 + 36, Bb, 128, 7, 7);
    blury_add_kernel<<<g, TPB, 0, stream>>>(Bb, A, k1 + 36, sc, ss, 128, 7, 7);
  }
  launch_conv_mfma(A, w22, b22, Bb, wsc, 128, 128, 128, 128, 1, stream);
  stats_kernel<<<4 * 128, TPB, 0, stream>>>(Bb, mc, sc, 128 * 128);
  stats_kernel<<<4 * 128, TPB, 0, stream>>>(s21, ms, ss, 128 * 128);
  {
    dim3 g(64, 4 * 128);
    affine_kernel<<<g, TPB, 0, stream>>>(Bb, mc, sc, ms, ss, 128 * 128);
  }
  launch_conv_mfma(Bb, w21, b21, A, wsc, 128, 64, 128, 128, 1, stream);

  // ---------------- level 2 -> 1 (256x256, 64ch) ----------------
  {
    long long n = 4LL * 64 * 256 * 256;
    up2_kernel<<<(int)(n / TPB), TPB, 0, stream>>>(A, Bb, 8, 8, n);
  }
  stats_kernel<<<4 * 64, TPB, 0, stream>>>(c12, mc, sc, 256 * 256);
  stats_kernel<<<4 * 64, TPB, 0, stream>>>(s12, ms, ss, 256 * 256);
  {
    long long n = 4LL * 64 * 128 * 128;
    pool2_kernel<<<(int)(n / TPB), TPB, 0, stream>>>(c12, P, 7, 7, n);
  }
  {
    dim3 g((unsigned)((64LL * 256 * 256) / TPB), 1, 4);
    blurx_kernel<<<g, TPB, 0, stream>>>(c12, P, k1 + 0, A, 64, 8, 8);
    blury_add_kernel<<<g, TPB, 0, stream>>>(A, Bb, k1 + 0, sc, ss, 64, 8, 8);
  }
  launch_conv_mfma(Bb, w12, b12, A, wsc, 64, 64, 256, 256, 1, stream);
  stats_kernel<<<4 * 64, TPB, 0, stream>>>(A, mc, sc, 256 * 256);
  stats_kernel<<<4 * 64, TPB, 0, stream>>>(s11, ms, ss, 256 * 256);
  {
    dim3 g(256, 4 * 64);
    affine_kernel<<<g, TPB, 0, stream>>>(A, mc, sc, ms, ss, 256 * 256);
  }
  conv3x3_c3_kernel<<<dim3(256, 1, 4), TPB, 0, stream>>>(A, w11, b11, (float*)d_out,
                                                         64, 256, 256);
}

// Round 3
// 1697.028 us; speedup vs baseline: 2.1901x; 1.1518x over previous
//
#include <hip/hip_runtime.h>
#include <math.h>

#define TPB 256

typedef __attribute__((ext_vector_type(8))) short s8v;   // 8 bf16 (MFMA A/B frag)
typedef __attribute__((ext_vector_type(4))) float f4v;   // 4 f32 (MFMA C/D frag)

__device__ __forceinline__ unsigned bf16r(float f) {
  unsigned u = __float_as_uint(f);
  return (u + 0x7fffu + ((u >> 16) & 1u)) >> 16;  // RNE fp32->bf16
}

// ---------------------------------------------------------------------------
// Per-sample separable 1D gaussian kernels (normalized), all 3 levels at once.
// ---------------------------------------------------------------------------
__global__ __launch_bounds__(128) void gauss1d_kernel(const float* __restrict__ alphas,
                                                      float* __restrict__ k1d) {
  int t = threadIdx.x;
  if (t >= 108) return;
  int lvl = t / 36;
  int rem = t - lvl * 36;
  int b = rem / 9;
  int j = rem - b * 9;
  float alpha = alphas[b * 3 + lvl];
  float k = floorf(floorf(alpha * 8.f) * 0.5f) * 2.f + 1.f;
  float r = (k - 1.f) * 0.5f;
  float sum = 0.f, val = 0.f;
  for (int u = 0; u < 9; ++u) {
    float d = (float)(u - 4);
    float g = expf(-(d * d) / 512.f);   // 2*sigma^2 = 512
    if (fabsf(d) > r) g = 0.f;
    if (u == j) val = g;
    sum += g;
  }
  k1d[(lvl * 4 + b) * 9 + j] = val / sum;
}

// ---------------------------------------------------------------------------
// Per-(b,c) mean + unbiased std over HW. One block per (b,c).
// ---------------------------------------------------------------------------
__global__ __launch_bounds__(TPB) void stats_kernel(const float* __restrict__ x,
                                                    float* __restrict__ mean,
                                                    float* __restrict__ stdv, int HW) {
  long long base = (long long)blockIdx.x * HW;
  float s = 0.f, q = 0.f;
  for (int i = threadIdx.x; i < HW; i += TPB) {
    float v = x[base + i];
    s += v;
    q = fmaf(v, v, q);
  }
#pragma unroll
  for (int off = 32; off > 0; off >>= 1) {
    s += __shfl_down(s, off, 64);
    q += __shfl_down(q, off, 64);
  }
  __shared__ float sm[8];
  int w = threadIdx.x >> 6, lane = threadIdx.x & 63;
  if (lane == 0) { sm[w * 2] = s; sm[w * 2 + 1] = q; }
  __syncthreads();
  if (threadIdx.x == 0) {
    float S = sm[0] + sm[2] + sm[4] + sm[6];
    float Q = sm[1] + sm[3] + sm[5] + sm[7];
    float m = S / (float)HW;
    float var = (Q - S * m) / (float)(HW - 1);
    mean[blockIdx.x] = m;
    stdv[blockIdx.x] = sqrtf(fmaxf(var, 0.f));
  }
}

// ---------------------------------------------------------------------------
// 2x2 mean pool
// ---------------------------------------------------------------------------
__global__ __launch_bounds__(TPB) void pool2_kernel(const float* __restrict__ src,
                                                    float* __restrict__ dst,
                                                    int lwh, int lhh, long long n) {
  long long i = (long long)blockIdx.x * TPB + threadIdx.x;
  if (i >= n) return;
  int Wh = 1 << lwh, Hh = 1 << lhh;
  int px = (int)(i & (Wh - 1));
  int py = (int)((i >> lwh) & (Hh - 1));
  long long bc = i >> (lwh + lhh);
  const float* sp = src + (bc << (lwh + lhh + 2)) + (long long)(py * 2) * (Wh * 2) + px * 2;
  dst[i] = 0.25f * (sp[0] + sp[1] + sp[Wh * 2] + sp[Wh * 2 + 1]);
}

// ---------------------------------------------------------------------------
// Nearest 2x upsample. lw/lh log2 of OUTPUT dims.
// ---------------------------------------------------------------------------
__global__ __launch_bounds__(TPB) void up2_kernel(const float* __restrict__ src,
                                                  float* __restrict__ dst,
                                                  int lw, int lh, long long n) {
  long long i = (long long)blockIdx.x * TPB + threadIdx.x;
  if (i >= n) return;
  int Wo = 1 << lw, Ho = 1 << lh;
  int x = (int)(i & (Wo - 1));
  int y = (int)((i >> lw) & (Ho - 1));
  long long bc = i >> (lw + lh);
  dst[i] = src[(bc << (lw + lh - 2)) + (long long)(y >> 1) * (Wo >> 1) + (x >> 1)];
}

// ---------------------------------------------------------------------------
// blurX of hh(c) (pool precomputed)
// ---------------------------------------------------------------------------
__global__ __launch_bounds__(TPB) void blurx_kernel(const float* __restrict__ src,
                                                    const float* __restrict__ pmap,
                                                    const float* __restrict__ k1d,
                                                    float* __restrict__ dst,
                                                    int C, int lw, int lh) {
  int b = blockIdx.z;
  float kb[9];
#pragma unroll
  for (int t = 0; t < 9; ++t) kb[t] = k1d[b * 9 + t];
  int W = 1 << lw;
  long long i = (long long)blockIdx.x * TPB + threadIdx.x;
  long long nper = (long long)C << (lw + lh);
  if (i >= nper) return;
  int x = (int)(i & (W - 1));
  long long rest = i >> lw;
  int y = (int)(rest & ((1 << lh) - 1));
  int c = (int)(rest >> lh);
  long long bc = (long long)b * C + c;
  const float* sp = src + (bc << (lw + lh)) + ((long long)y << lw);
  const float* pp = pmap + (bc << (lw + lh - 2)) + ((long long)(y >> 1) << (lw - 1));
  float s = 0.f;
#pragma unroll
  for (int t = 0; t < 9; ++t) {
    int px = x + t - 4;
    px = px < 0 ? 0 : (px > W - 1 ? W - 1 : px);
    s = fmaf(kb[t], sp[px] - pp[px >> 1], s);
  }
  dst[(bc << (lw + lh)) + ((long long)y << lw) + x] = s;
}

// ---------------------------------------------------------------------------
// blurY + scale + add
// ---------------------------------------------------------------------------
__global__ __launch_bounds__(TPB) void blury_add_kernel(const float* __restrict__ tmp,
                                                        float* __restrict__ out,
                                                        const float* __restrict__ k1d,
                                                        const float* __restrict__ stdc,
                                                        const float* __restrict__ stds,
                                                        int C, int lw, int lh) {
  int b = blockIdx.z;
  float kb[9];
#pragma unroll
  for (int t = 0; t < 9; ++t) kb[t] = k1d[b * 9 + t];
  int W = 1 << lw, H = 1 << lh;
  long long i = (long long)blockIdx.x * TPB + threadIdx.x;
  long long nper = (long long)C << (lw + lh);
  if (i >= nper) return;
  int x = (int)(i & (W - 1));
  long long rest = i >> lw;
  int y = (int)(rest & (H - 1));
  int c = (int)(rest >> lh);
  int bc = b * C + c;
  float a = stds[bc] / (stdc[bc] + 1e-5f);
  const float* tp = tmp + ((long long)bc << (lw + lh)) + x;
  float s = 0.f;
#pragma unroll
  for (int t = 0; t < 9; ++t) {
    int py = y + t - 4;
    py = py < 0 ? 0 : (py > H - 1 ? H - 1 : py);
    s = fmaf(kb[t], tp[(long long)py << lw], s);
  }
  out[((long long)bc << (lw + lh)) + ((long long)y << lw) + x] += a * s;
}

// ---------------------------------------------------------------------------
// In-place AdaIN affine
// ---------------------------------------------------------------------------
__global__ __launch_bounds__(TPB) void affine_kernel(float* __restrict__ x,
                                                     const float* __restrict__ mc,
                                                     const float* __restrict__ sc,
                                                     const float* __restrict__ ms,
                                                     const float* __restrict__ ss, int HW) {
  int bc = blockIdx.y;
  float a = ss[bc] / (sc[bc] + 1e-5f);
  float d = ms[bc] - mc[bc] * a;
  long long base = (long long)bc * HW;
  for (int i = blockIdx.x * TPB + threadIdx.x; i < HW; i += gridDim.x * TPB)
    x[base + i] = fmaf(x[base + i], a, d);
}

// ---------------------------------------------------------------------------
// bias + relu (epilogue for split-K atomic convs)
// ---------------------------------------------------------------------------
__global__ __launch_bounds__(TPB) void bias_relu_kernel(float* __restrict__ x,
                                                        const float* __restrict__ bias,
                                                        int HW, int C, long long n) {
  long long i = (long long)blockIdx.x * TPB + threadIdx.x;
  if (i >= n) return;
  int c = (int)((i / HW) % C);
  x[i] = fmaxf(x[i] + bias[c], 0.f);
}

// ---------------------------------------------------------------------------
// Weight pre-split: fp32 [Cout][Cin][3][3] -> bf16 hi/lo planes laid out in
// MFMA A-fragment order: plane[( (t*(Cout/16)+cof)*(Cin/32)+cik )*512 + lane*8 + j]
//   co = cof*16 + (lane&15), ci = cik*32 + (lane>>4)*8 + j
// ---------------------------------------------------------------------------
__global__ __launch_bounds__(TPB) void wsplit_kernel(const float* __restrict__ w,
                                                     short* __restrict__ wt,
                                                     int Cin, int Cout) {
  int nk = Cin >> 5, nc = Cout >> 4;
  int nf = 9 * nc * nk;
  int total = nf << 6;
  int planeStride = nf << 9;  // shorts
  for (int i = blockIdx.x * TPB + threadIdx.x; i < total; i += gridDim.x * TPB) {
    int l = i & 63;
    int f = i >> 6;
    int cik = f % nk;
    int rem = f / nk;
    int cof = rem % nc;
    int t = rem / nc;
    int co = (cof << 4) + (l & 15);
    int ci = (cik << 5) + ((l >> 4) << 3);
    s8v hv, lv;
#pragma unroll
    for (int j = 0; j < 8; ++j) {
      float v = w[((long long)co * Cin + ci + j) * 9 + t];
      unsigned h = bf16r(v);
      float r = v - __uint_as_float(h << 16);
      hv[j] = (short)h;
      lv[j] = (short)bf16r(r);
    }
    long long o = ((long long)f << 9) + (l << 3);
    *(s8v*)(wt + o) = hv;
    *(s8v*)(wt + planeStride + o) = lv;
  }
}

// ---------------------------------------------------------------------------
// bf16x2-split (3-MFMA) implicit-GEMM 3x3 conv, reflect pad 1, NCHW fp32.
// Block: 64 co x 64 px (16 wide x 4 tall tile). 4 waves, wave = 16co x 64px
// (m=1, n=4 frags of mfma_f32_16x16x32_bf16) -> waves split by CO, so each
// wave loads only its own weight fragments (no intra-block duplication) and
// the staged input is reused by all 64 co.
// K = ci chunks of 32. Staging region 18x6x32ci, hi/lo bf16, ci padded to 40.
// Pow2-only stage indexing; interior via float4 loads; full RNE conversion.
// Compute: c-outer with 6-row register cache -> exactly 36 ds_read_b128 and
// 18 weight dwordx4 loads per wave per chunk.
// ---------------------------------------------------------------------------
template <bool RELU, bool ATOMIC>
__global__ __launch_bounds__(TPB, 4) void conv_mfma_kernel(
    const float* __restrict__ in, const short* __restrict__ wt,
    const float* __restrict__ bias, float* __restrict__ out,
    int Cin, int Cout, int H, int W, int ciPer, int ksplit) {
  __shared__ __align__(16) short sIn[2][4320];  // [plane][(iy*18+ix)*40 + ci2]

  const int tid = threadIdx.x;
  const int l = tid & 63;
  const int wv = tid >> 6;
  const int xln = l & 15;
  const int kg = l >> 4;
  const int tilesX = W >> 4;
  const int tx0 = (blockIdx.x % tilesX) << 4;
  const int ty0 = (blockIdx.x / tilesX) << 2;
  const int co0 = blockIdx.y << 6;
  const int b = blockIdx.z / ksplit;
  const int kz = blockIdx.z % ksplit;
  const int ci0 = kz * ciPer;
  const long long HW = (long long)H * W;
  const long long inB = (long long)b * Cin * HW;

  const int nk = Cin >> 5;
  const int nc = Cout >> 4;
  const int planeStride = (9 * nc * nk) << 9;  // shorts
  const int cof = (co0 >> 4) + wv;             // this wave's co-fragment

  f4v acc[4];
#pragma unroll
  for (int n = 0; n < 4; ++n) acc[n] = (f4v){0.f, 0.f, 0.f, 0.f};

  for (int cc = 0; cc < ciPer; cc += 32) {
    const int cib = ci0 + cc;
    __syncthreads();
    // ---- interior columns (ix 1..16): 6 rows x 16 ci-pairs x 4 quads ----
    for (int i = tid; i < 384; i += TPB) {
      int q = i & 3;
      int cp = (i >> 2) & 15;
      int iy = i >> 6;
      int gy = ty0 - 1 + iy;
      gy = gy < 0 ? -gy : (gy >= H ? 2 * H - 2 - gy : gy);
      int gx = tx0 + (q << 2);
      long long gp = inB + (long long)(cib + cp * 2) * HW + (long long)gy * W + gx;
      float4 f0 = *(const float4*)(in + gp);
      float4 f1 = *(const float4*)(in + gp + HW);
      float a0[4] = {f0.x, f0.y, f0.z, f0.w};
      float a1[4] = {f1.x, f1.y, f1.z, f1.w};
      int idx = (iy * 18 + 1 + (q << 2)) * 40 + cp * 2;
#pragma unroll
      for (int j = 0; j < 4; ++j) {
        unsigned h0 = bf16r(a0[j]), h1 = bf16r(a1[j]);
        float r0 = a0[j] - __uint_as_float(h0 << 16);
        float r1 = a1[j] - __uint_as_float(h1 << 16);
        unsigned lo0 = bf16r(r0), lo1 = bf16r(r1);
        *(unsigned*)&sIn[0][idx + j * 40] = h0 | (h1 << 16);
        *(unsigned*)&sIn[1][idx + j * 40] = lo0 | (lo1 << 16);
      }
    }
    // ---- halo columns (ix 0 and 17): 6 rows x 16 ci-pairs x 2 ----
    if (tid < 192) {
      int col = tid & 1;
      int cp = (tid >> 1) & 15;
      int iy = tid >> 5;
      int gy = ty0 - 1 + iy;
      gy = gy < 0 ? -gy : (gy >= H ? 2 * H - 2 - gy : gy);
      int gx = col ? tx0 + 16 : tx0 - 1;
      gx = gx < 0 ? -gx : (gx >= W ? 2 * W - 2 - gx : gx);
      long long gp = inB + (long long)(cib + cp * 2) * HW + (long long)gy * W + gx;
      float f0 = in[gp], f1 = in[gp + HW];
      unsigned h0 = bf16r(f0), h1 = bf16r(f1);
      float r0 = f0 - __uint_as_float(h0 << 16);
      float r1 = f1 - __uint_as_float(h1 << 16);
      unsigned lo0 = bf16r(r0), lo1 = bf16r(r1);
      int idx = (iy * 18 + (col ? 17 : 0)) * 40 + cp * 2;
      *(unsigned*)&sIn[0][idx] = h0 | (h1 << 16);
      *(unsigned*)&sIn[1][idx] = lo0 | (lo1 << 16);
    }
    __syncthreads();

    const int cik = cib >> 5;
#pragma unroll
    for (int c = 0; c < 3; ++c) {
      s8v bh[6], bl[6];
#pragma unroll
      for (int ro = 0; ro < 6; ++ro) {
        int o = (ro * 18 + xln + c) * 40 + kg * 8;
        bh[ro] = *(const s8v*)&sIn[0][o];
        bl[ro] = *(const s8v*)&sIn[1][o];
      }
#pragma unroll
      for (int r = 0; r < 3; ++r) {
        const int t = r * 3 + c;
        const long long f = (long long)(t * nc + cof) * nk + cik;
        const short* wp = wt + (f << 9) + (l << 3);
        s8v ah = *(const s8v*)wp;
        s8v al = *(const s8v*)(wp + planeStride);
#pragma unroll
        for (int n = 0; n < 4; ++n) {
          acc[n] = __builtin_amdgcn_mfma_f32_16x16x32_bf16(ah, bh[n + r], acc[n], 0, 0, 0);
          acc[n] = __builtin_amdgcn_mfma_f32_16x16x32_bf16(ah, bl[n + r], acc[n], 0, 0, 0);
          acc[n] = __builtin_amdgcn_mfma_f32_16x16x32_bf16(al, bh[n + r], acc[n], 0, 0, 0);
        }
      }
    }
  }

  // ---- epilogue: C/D col=lane&15 (px-x), row=(lane>>4)*4+reg (co) ----
  const int cb = co0 + wv * 16 + kg * 4;
#pragma unroll
  for (int j = 0; j < 4; ++j) {
    const int co = cb + j;
    const float bv = ATOMIC ? 0.f : bias[co];
    float* op = out + ((long long)b * Cout + co) * HW + (long long)ty0 * W + tx0 + xln;
#pragma unroll
    for (int n = 0; n < 4; ++n) {
      float v = acc[n][j];
      if (ATOMIC) {
        atomicAdd(op + (long long)n * W, v);
      } else {
        v += bv;
        if (RELU) v = fmaxf(v, 0.f);
        op[(long long)n * W] = v;
      }
    }
  }
}

// ---------------------------------------------------------------------------
// Small final conv: Cout=3 (fp32 path, unchanged)
// ---------------------------------------------------------------------------
__global__ __launch_bounds__(TPB) void conv3x3_c3_kernel(
    const float* __restrict__ in, const float* __restrict__ wgt,
    const float* __restrict__ bias, float* __restrict__ out,
    int Cin, int H, int W) {
  __shared__ __align__(16) float tIn[8][18][20];
  const int tid = threadIdx.x;
  const int tilesX = W >> 4;
  const int tx0 = (blockIdx.x % tilesX) << 4;
  const int ty0 = (blockIdx.x / tilesX) << 4;
  const int b = blockIdx.z;
  const int tx = tid & 15, ty = tid >> 4;

  float acc[3] = {0.f, 0.f, 0.f};
  const long long inB = (long long)b * Cin * H * W;

  for (int cc = 0; cc < Cin; cc += 8) {
    __syncthreads();
    for (int i = tid; i < 8 * 324; i += TPB) {
      int ci = i / 324;
      int rem = i - ci * 324;
      int iy = rem / 18;
      int ix = rem - iy * 18;
      int gy = ty0 - 1 + iy;
      gy = gy < 0 ? -gy : (gy >= H ? 2 * H - 2 - gy : gy);
      int gx = tx0 - 1 + ix;
      gx = gx < 0 ? -gx : (gx >= W ? 2 * W - 2 - gx : gx);
      tIn[ci][iy][ix] = in[inB + (long long)(cc + ci) * H * W + (long long)gy * W + gx];
    }
    __syncthreads();
#pragma unroll 2
    for (int ci = 0; ci < 8; ++ci) {
#pragma unroll
      for (int r = 0; r < 3; ++r)
#pragma unroll
        for (int c = 0; c < 3; ++c) {
          float v = tIn[ci][ty + r][tx + c];
          int t = r * 3 + c;
          acc[0] = fmaf(wgt[((long long)(0 * Cin) + cc + ci) * 9 + t], v, acc[0]);
          acc[1] = fmaf(wgt[((long long)(1 * Cin) + cc + ci) * 9 + t], v, acc[1]);
          acc[2] = fmaf(wgt[((long long)(2 * Cin) + cc + ci) * 9 + t], v, acc[2]);
        }
    }
  }
  const long long HWl = (long long)H * W;
#pragma unroll
  for (int co = 0; co < 3; ++co)
    out[((long long)b * 3 + co) * HWl + (long long)(ty0 + ty) * W + tx0 + tx] =
        acc[co] + bias[co];
}

// ---------------------------------------------------------------------------
static inline void launch_conv_mfma(const float* in, const float* w, const float* bias,
                                    float* out, short* wsc, int Cin, int Cout,
                                    int H, int W, int ksplit, hipStream_t s) {
  int total = 9 * (Cout >> 4) * (Cin >> 5) * 64;
  int wgrid = (total + TPB - 1) / TPB;
  wsplit_kernel<<<wgrid, TPB, 0, s>>>(w, wsc, Cin, Cout);
  dim3 grid((W >> 4) * (H >> 2), Cout >> 6, 4 * ksplit);
  if (ksplit > 1)
    conv_mfma_kernel<false, true><<<grid, TPB, 0, s>>>(in, wsc, bias, out, Cin, Cout,
                                                       H, W, Cin / ksplit, ksplit);
  else
    conv_mfma_kernel<true, false><<<grid, TPB, 0, s>>>(in, wsc, bias, out, Cin, Cout,
                                                       H, W, Cin, 1);
}

extern "C" void kernel_launch(void* const* d_in, const int* in_sizes, int n_in,
                              void* d_out, int out_size, void* d_ws, size_t ws_size,
                              hipStream_t stream) {
  const float* x   = (const float*)d_in[0];
  const float* c34 = (const float*)d_in[1];
  const float* c22 = (const float*)d_in[2];
  const float* c12 = (const float*)d_in[3];
  const float* s34 = (const float*)d_in[4];
  const float* s31 = (const float*)d_in[5];
  const float* s22 = (const float*)d_in[6];
  const float* s21 = (const float*)d_in[7];
  const float* s12 = (const float*)d_in[8];
  const float* s11 = (const float*)d_in[9];
  const float* alphas = (const float*)d_in[10];
  const float* w41 = (const float*)d_in[11]; const float* b41 = (const float*)d_in[12];
  const float* w34 = (const float*)d_in[13]; const float* b34 = (const float*)d_in[14];
  const float* w33 = (const float*)d_in[15]; const float* b33 = (const float*)d_in[16];
  const float* w32 = (const float*)d_in[17]; const float* b32 = (const float*)d_in[18];
  const float* w31 = (const float*)d_in[19]; const float* b31 = (const float*)d_in[20];
  const float* w22 = (const float*)d_in[21]; const float* b22 = (const float*)d_in[22];
  const float* w21 = (const float*)d_in[23]; const float* b21 = (const float*)d_in[24];
  const float* w12 = (const float*)d_in[25]; const float* b12 = (const float*)d_in[26];
  const float* w11 = (const float*)d_in[27]; const float* b11 = (const float*)d_in[28];

  // workspace layout (floats)
  float* A  = (float*)d_ws;            // 16M floats (64 MB)
  float* Bb = A + 16777216;            // 16M floats (64 MB)
  float* P  = Bb + 16777216;           // 4M floats (16 MB): pool map / wsplit scratch
  float* mc = P + 4194304;
  float* sc = mc + 2048;
  float* ms = sc + 2048;
  float* ss = ms + 2048;
  float* k1 = ss + 2048;               // 108 floats: [3][4][9]
  short* wsc = (short*)P;              // split-weight scratch (max 4.72 MB, fits in P)

  gauss1d_kernel<<<1, 128, 0, stream>>>(alphas, k1);

  // ---------------- level 4 -> 3 (64x64, 256ch) ----------------
  hipMemsetAsync(A, 0, 4LL * 256 * 32 * 32 * 4, stream);
  launch_conv_mfma(x, w41, b41, A, wsc, 512, 256, 32, 32, 4, stream);
  {
    long long n = 4LL * 256 * 1024;
    bias_relu_kernel<<<(int)(n / TPB), TPB, 0, stream>>>(A, b41, 1024, 256, n);
  }
  {
    long long n = 4LL * 256 * 64 * 64;
    up2_kernel<<<(int)(n / TPB), TPB, 0, stream>>>(A, Bb, 6, 6, n);
  }
  stats_kernel<<<4 * 256, TPB, 0, stream>>>(c34, mc, sc, 64 * 64);
  stats_kernel<<<4 * 256, TPB, 0, stream>>>(s34, ms, ss, 64 * 64);
  {
    long long n = 4LL * 256 * 32 * 32;
    pool2_kernel<<<(int)(n / TPB), TPB, 0, stream>>>(c34, P, 5, 5, n);
  }
  {
    dim3 g((unsigned)((256LL * 64 * 64) / TPB), 1, 4);
    blurx_kernel<<<g, TPB, 0, stream>>>(c34, P, k1 + 72, A, 256, 6, 6);
    blury_add_kernel<<<g, TPB, 0, stream>>>(A, Bb, k1 + 72, sc, ss, 256, 6, 6);
  }
  launch_conv_mfma(Bb, w34, b34, A, wsc, 256, 256, 64, 64, 1, stream);
  launch_conv_mfma(A, w33, b33, Bb, wsc, 256, 256, 64, 64, 1, stream);
  launch_conv_mfma(Bb, w32, b32, A, wsc, 256, 256, 64, 64, 1, stream);
  stats_kernel<<<4 * 256, TPB, 0, stream>>>(A, mc, sc, 64 * 64);
  stats_kernel<<<4 * 256, TPB, 0, stream>>>(s31, ms, ss, 64 * 64);
  {
    dim3 g(16, 4 * 256);
    affine_kernel<<<g, TPB, 0, stream>>>(A, mc, sc, ms, ss, 64 * 64);
  }
  hipMemsetAsync(Bb, 0, 4LL * 128 * 64 * 64 * 4, stream);
  launch_conv_mfma(A, w31, b31, Bb, wsc, 256, 128, 64, 64, 2, stream);
  {
    long long n = 4LL * 128 * 4096;
    bias_relu_kernel<<<(int)(n / TPB), TPB, 0, stream>>>(Bb, b31, 4096, 128, n);
  }

  // ---------------- level 3 -> 2 (128x128, 128ch) ----------------
  {
    long long n = 4LL * 128 * 128 * 128;
    up2_kernel<<<(int)(n / TPB), TPB, 0, stream>>>(Bb, A, 7, 7, n);
  }
  stats_kernel<<<4 * 128, TPB, 0, stream>>>(c22, mc, sc, 128 * 128);
  stats_kernel<<<4 * 128, TPB, 0, stream>>>(s22, ms, ss, 128 * 128);
  {
    long long n = 4LL * 128 * 64 * 64;
    pool2_kernel<<<(int)(n / TPB), TPB, 0, stream>>>(c22, P, 6, 6, n);
  }
  {
    dim3 g((unsigned)((128LL * 128 * 128) / TPB), 1, 4);
    blurx_kernel<<<g, TPB, 0, stream>>>(c22, P, k1 + 36, Bb, 128, 7, 7);
    blury_add_kernel<<<g, TPB, 0, stream>>>(Bb, A, k1 + 36, sc, ss, 128, 7, 7);
  }
  launch_conv_mfma(A, w22, b22, Bb, wsc, 128, 128, 128, 128, 1, stream);
  stats_kernel<<<4 * 128, TPB, 0, stream>>>(Bb, mc, sc, 128 * 128);
  stats_kernel<<<4 * 128, TPB, 0, stream>>>(s21, ms, ss, 128 * 128);
  {
    dim3 g(64, 4 * 128);
    affine_kernel<<<g, TPB, 0, stream>>>(Bb, mc, sc, ms, ss, 128 * 128);
  }
  launch_conv_mfma(Bb, w21, b21, A, wsc, 128, 64, 128, 128, 1, stream);

  // ---------------- level 2 -> 1 (256x256, 64ch) ----------------
  {
    long long n = 4LL * 64 * 256 * 256;
    up2_kernel<<<(int)(n / TPB), TPB, 0, stream>>>(A, Bb, 8, 8, n);
  }
  stats_kernel<<<4 * 64, TPB, 0, stream>>>(c12, mc, sc, 256 * 256);
  stats_kernel<<<4 * 64, TPB, 0, stream>>>(s12, ms, ss, 256 * 256);
  {
    long long n = 4LL * 64 * 128 * 128;
    pool2_kernel<<<(int)(n / TPB), TPB, 0, stream>>>(c12, P, 7, 7, n);
  }
  {
    dim3 g((unsigned)((64LL * 256 * 256) / TPB), 1, 4);
    blurx_kernel<<<g, TPB, 0, stream>>>(c12, P, k1 + 0, A, 64, 8, 8);
    blury_add_kernel<<<g, TPB, 0, stream>>>(A, Bb, k1 + 0, sc, ss, 64, 8, 8);
  }
  launch_conv_mfma(Bb, w12, b12, A, wsc, 64, 64, 256, 256, 1, stream);
  stats_kernel<<<4 * 64, TPB, 0, stream>>>(A, mc, sc, 256 * 256);
  stats_kernel<<<4 * 64, TPB, 0, stream>>>(s11, ms, ss, 256 * 256);
  {
    dim3 g(256, 4 * 64);
    affine_kernel<<<g, TPB, 0, stream>>>(A, mc, sc, ms, ss, 256 * 256);
  }
  conv3x3_c3_kernel<<<dim3(256, 1, 4), TPB, 0, stream>>>(A, w11, b11, (float*)d_out,
                                                         64, 256, 256);
}